// Round 2
// baseline (369.357 us; speedup 1.0000x reference)
//
#include <hip/hip_runtime.h>
#include <hip/hip_bf16.h>
#include <math.h>

using bf16 = __hip_bfloat16;
typedef __attribute__((ext_vector_type(8))) short short8;   // 8 bf16 = 16B
typedef __attribute__((ext_vector_type(4))) float floatx4;  // MFMA C/D frag

#define GLOBAL_U32 const __attribute__((address_space(1))) unsigned int*
#define LDS_U32    __attribute__((address_space(3))) unsigned int*

// ---------------------------------------------------------------------------
// fp32 -> bf16 conversion
// ---------------------------------------------------------------------------
__global__ __launch_bounds__(256)
void convert_f32_bf16(const float* __restrict__ src, bf16* __restrict__ dst,
                      long n) {
    long i = (long)blockIdx.x * 256 + threadIdx.x;
    long stride = (long)gridDim.x * 256;
    const float4* s = (const float4*)src;
    for (long k = i; k < n / 4; k += stride) {
        float4 v = s[k];
        bf16 o[4] = {__float2bfloat16(v.x), __float2bfloat16(v.y),
                     __float2bfloat16(v.z), __float2bfloat16(v.w)};
        *(ulonglong1*)(dst + k * 4) = *(ulonglong1*)o;
    }
}

// ---------------------------------------------------------------------------
// GEMM (128x128 tile, m97 structure): kept for the out-projection
// ---------------------------------------------------------------------------
template <typename OUT_T>
__global__ __launch_bounds__(256)
void gemm_bt(const bf16* __restrict__ A, const bf16* __restrict__ W,
             OUT_T* __restrict__ C, int M, int N, int K) {
    __shared__ __align__(16) bf16 As[128 * 64];
    __shared__ __align__(16) bf16 Bs[128 * 64];

    const int tid  = threadIdx.x;
    const int lane = tid & 63;
    const int wave = tid >> 6;
    const int l15  = lane & 15;
    const int quad = lane >> 4;
    const int wm   = (wave & 1) * 64;
    const int wn   = (wave >> 1) * 64;
    const int sw   = l15 & 7;

    const long m0 = (long)blockIdx.y * 128;
    const long n0 = (long)blockIdx.x * 128;
    const bf16* Ab = A + m0 * K;
    const bf16* Wb = W + n0 * K;

    floatx4 acc[4][4] = {};

    for (int kt = 0; kt < K; kt += 64) {
        __syncthreads();
#pragma unroll
        for (int i = 0; i < 4; ++i) {
            int L = i * 256 + tid;
            int row = L >> 3, g = L & 7;
            int gs = g ^ (row & 7);
            __builtin_amdgcn_global_load_lds(
                (GLOBAL_U32)(Ab + (long)row * K + kt + gs * 8),
                (LDS_U32)(As + L * 8), 16, 0, 0);
            __builtin_amdgcn_global_load_lds(
                (GLOBAL_U32)(Wb + (long)row * K + kt + gs * 8),
                (LDS_U32)(Bs + L * 8), 16, 0, 0);
        }
        __syncthreads();

#pragma unroll
        for (int h = 0; h < 2; ++h) {
            short8 af[4], bfg[4];
#pragma unroll
            for (int mt = 0; mt < 4; ++mt)
                af[mt] = *(const short8*)(As + (wm + mt * 16 + l15) * 64 +
                                          ((h * 4 + quad) ^ sw) * 8);
#pragma unroll
            for (int nt = 0; nt < 4; ++nt)
                bfg[nt] = *(const short8*)(Bs + (wn + nt * 16 + l15) * 64 +
                                           ((h * 4 + quad) ^ sw) * 8);
#pragma unroll
            for (int mt = 0; mt < 4; ++mt)
#pragma unroll
                for (int nt = 0; nt < 4; ++nt)
                    acc[mt][nt] = __builtin_amdgcn_mfma_f32_16x16x32_bf16(
                        af[mt], bfg[nt], acc[mt][nt], 0, 0, 0);
        }
    }

#pragma unroll
    for (int mt = 0; mt < 4; ++mt)
#pragma unroll
        for (int nt = 0; nt < 4; ++nt)
#pragma unroll
            for (int r = 0; r < 4; ++r) {
                long row = m0 + wm + mt * 16 + quad * 4 + r;
                long col = n0 + wn + nt * 16 + l15;
                float v = acc[mt][nt][r];
                if (!isfinite(v)) v = 1000.0f;
                C[row * N + col] = (OUT_T)v;
            }
}

// ---------------------------------------------------------------------------
// GEMM 256x256 tile, 4-phase/K-tile counted-vmcnt schedule (T1+T2+T3+T4+T5).
// C[M,N] = A[M,K] * W[N,K]^T, bf16 in/out, fp32 accum.
//
// 512 threads = 8 waves (2M x 4N), per-wave C = 128x64.
// LDS 128 KiB = 2 buf x (A[256][64] + B[256][64]) bf16, XOR-granule swizzle.
// Half-tile h: 0=A rows 0-127, 1=A rows 128-255, 2=B 0-127, 3=B 128-255;
// one half = 2 global_load_lds/thread.
//
// Stage schedule for tile t (buf c = t&1), all issues in phase preambles:
//   P0: t+1.h1, t+1.h3 -> buf c^1   (tile t-1's readers sealed at its end)
//   P2: t+2.h2 -> buf c             (all B reads of tile t sealed at P1-POST)
//   P3: t+2.h0 -> buf c             (all A reads of tile t sealed at P2-POST)
// A-frags read at point of use: af rows +0 at P0, rows +64 at P2 (af reused).
// End-of-tile s_waitcnt vmcnt(4) keeps t+2.{h2,h0} in flight across the
// barrier; vmcnt(0) only at the tail tile.
// ---------------------------------------------------------------------------
#define MFMA_QUAD(mh, nh)                                                     \
    __builtin_amdgcn_s_setprio(1);                                            \
    _Pragma("unroll")                                                         \
    for (int mf = 0; mf < 4; ++mf)                                            \
        _Pragma("unroll")                                                     \
        for (int nf = 0; nf < 2; ++nf)                                        \
            _Pragma("unroll")                                                 \
            for (int ks = 0; ks < 2; ++ks)                                    \
                acc[(mh) * 4 + mf][(nh) * 2 + nf] =                           \
                    __builtin_amdgcn_mfma_f32_16x16x32_bf16(                  \
                        af[mf][ks], bf_[(nh) * 2 + nf][ks],                   \
                        acc[(mh) * 4 + mf][(nh) * 2 + nf], 0, 0, 0);          \
    __builtin_amdgcn_s_setprio(0);

#define PHASE_PRE()                                                           \
    __builtin_amdgcn_sched_barrier(0);                                        \
    __builtin_amdgcn_s_barrier();                                             \
    asm volatile("s_waitcnt lgkmcnt(0)" ::: "memory");                        \
    __builtin_amdgcn_sched_barrier(0);

#define PHASE_POST()                                                          \
    __builtin_amdgcn_sched_barrier(0);                                        \
    __builtin_amdgcn_s_barrier();

__global__ __launch_bounds__(512)
void gemm_bt_256(const bf16* __restrict__ A, const bf16* __restrict__ W,
                 bf16* __restrict__ C, int M, int N, int K) {
    __shared__ __align__(16) bf16 smem[65536];   // 128 KiB

    const int tid  = threadIdx.x;
    const int lane = tid & 63;
    const int wave = tid >> 6;
    const int l15  = lane & 15;
    const int quad = lane >> 4;
    const int sw   = l15 & 7;
    const int wm   = wave >> 2;          // 0..1  (M half of tile)
    const int wn   = wave & 3;           // 0..3  (N quarter)

    // XCD-aware bijective swizzle (grid is a multiple of 8)
    const int cpx = gridDim.x >> 3;
    const int id  = blockIdx.x;
    const int wg  = (id & 7) * cpx + (id >> 3);
    const int tn  = N >> 8;
    const long m0 = (long)(wg / tn) << 8;
    const long n0 = (long)(wg % tn) << 8;
    const bf16* Ab = A + m0 * K;
    const bf16* Wb = W + n0 * K;
    const int NT = K >> 6;               // K-tiles of 64 (NT >= 2)

    auto stage_half = [&](int tt, int h) {
        bf16* lb = smem + ((tt & 1) << 15) + ((h & 2) << 13) + ((h & 1) << 13);
        const bf16* src = ((h & 2) ? Wb : Ab) + (((long)(h & 1)) << 7) * K +
                          ((long)tt << 6);
#pragma unroll
        for (int it = 0; it < 2; ++it) {
            int L = (it << 9) + tid;
            int row = L >> 3, g = L & 7;
            int gs = g ^ (row & 7);       // inverse swizzle on global source
            __builtin_amdgcn_global_load_lds(
                (GLOBAL_U32)(src + (long)row * K + (gs << 3)),
                (LDS_U32)(lb + (L << 3)), 16, 0, 0);
        }
    };

    floatx4 acc[8][4] = {};
    short8 af[4][2], bf_[4][2];
    const int awoff = ((wm << 7) + l15) << 6;   // (wm*128 + l15) * 64
    const int bwoff = ((wn << 6) + l15) << 6;   // (wn*64  + l15) * 64
    const int k0 = (quad ^ sw) << 3;
    const int k1 = ((4 + quad) ^ sw) << 3;

    // prologue: tile0 fully; tile1 h2,h0 (matches steady-state issue ages)
    stage_half(0, 0); stage_half(0, 1); stage_half(0, 2); stage_half(0, 3);
    if (NT > 1) { stage_half(1, 2); stage_half(1, 0); }
    asm volatile("s_waitcnt vmcnt(4)" ::: "memory");
    __builtin_amdgcn_sched_barrier(0);
    __builtin_amdgcn_s_barrier();

    for (int t = 0; t < NT; ++t) {
        const bf16* Asb = smem + ((t & 1) << 15);
        const bf16* Bsb = Asb + 16384;

        // -------- phase 0: quadrant (0,0); A rows +0 --------
#pragma unroll
        for (int mf = 0; mf < 4; ++mf) {
            af[mf][0] = *(const short8*)(Asb + awoff + (mf << 10) + k0);
            af[mf][1] = *(const short8*)(Asb + awoff + (mf << 10) + k1);
        }
#pragma unroll
        for (int nf = 0; nf < 2; ++nf) {
            bf_[nf][0] = *(const short8*)(Bsb + bwoff + (nf << 10) + k0);
            bf_[nf][1] = *(const short8*)(Bsb + bwoff + (nf << 10) + k1);
        }
        if (t + 1 < NT) { stage_half(t + 1, 1); stage_half(t + 1, 3); }
        PHASE_PRE();
        MFMA_QUAD(0, 0);
        PHASE_POST();

        // -------- phase 1: quadrant (0,1) --------
#pragma unroll
        for (int nf = 2; nf < 4; ++nf) {
            bf_[nf][0] = *(const short8*)(Bsb + bwoff + (nf << 10) + k0);
            bf_[nf][1] = *(const short8*)(Bsb + bwoff + (nf << 10) + k1);
        }
        PHASE_PRE();
        MFMA_QUAD(0, 1);
        PHASE_POST();

        // -------- phase 2: quadrant (1,0); A rows +64 (af reused) --------
#pragma unroll
        for (int mf = 0; mf < 4; ++mf) {
            af[mf][0] = *(const short8*)(Asb + awoff + ((mf + 4) << 10) + k0);
            af[mf][1] = *(const short8*)(Asb + awoff + ((mf + 4) << 10) + k1);
        }
        if (t + 2 < NT) stage_half(t + 2, 2);
        PHASE_PRE();
        MFMA_QUAD(1, 0);
        PHASE_POST();

        // -------- phase 3: quadrant (1,1) --------
        if (t + 2 < NT) stage_half(t + 2, 0);
        PHASE_PRE();
        MFMA_QUAD(1, 1);
        __builtin_amdgcn_sched_barrier(0);
        // counted vmcnt at the tile boundary: keep t+2.{h2,h0} in flight.
        if (t + 2 < NT) {
            asm volatile("s_waitcnt vmcnt(4)" ::: "memory");
        } else if (t + 1 < NT) {
            asm volatile("s_waitcnt vmcnt(0)" ::: "memory");
        }
        __builtin_amdgcn_sched_barrier(0);
        __builtin_amdgcn_s_barrier();
    }

    // epilogue: C/D layout col = lane&15, row = quad*4 + r
#pragma unroll
    for (int mf = 0; mf < 8; ++mf)
#pragma unroll
        for (int nf = 0; nf < 4; ++nf)
#pragma unroll
            for (int r = 0; r < 4; ++r) {
                long row = m0 + wm * 128 + mf * 16 + quad * 4 + r;
                long col = n0 + wn * 64 + nf * 16 + l15;
                C[row * N + col] = __float2bfloat16(acc[mf][nf][r]);
            }
}

// ---------------------------------------------------------------------------
// Transpose V: qkv[token][4096 + h*128 + d] -> Vt[(b*16+h)*128 + d][s]
// ---------------------------------------------------------------------------
__global__ __launch_bounds__(256)
void transpose_v(const bf16* __restrict__ qkv, bf16* __restrict__ Vt) {
    __shared__ bf16 t[32][33];
    const int bh = blockIdx.z;
    const int b = bh >> 4, h = bh & 15;
    const int s0 = blockIdx.x * 32, d0 = blockIdx.y * 32;
    const int r = threadIdx.x >> 5, c = threadIdx.x & 31;
#pragma unroll
    for (int i = 0; i < 4; ++i) {
        int s = s0 + r + i * 8;
        t[r + i * 8][c] = qkv[((long)(b * 2048 + s)) * 6144 + 4096 + h * 128 + d0 + c];
    }
    __syncthreads();
#pragma unroll
    for (int i = 0; i < 4; ++i) {
        int d = d0 + r + i * 8;
        Vt[((long)bh * 128 + d) * 2048 + s0 + c] = t[c][r + i * 8];
    }
}

// ---------------------------------------------------------------------------
// Flash attention v3, causal. 1D grid (1024) heavy-qt-first.
// ---------------------------------------------------------------------------
__global__ __launch_bounds__(256)
void attn_kernel(const bf16* __restrict__ qkv, const bf16* __restrict__ Vt,
                 bf16* __restrict__ O) {
    constexpr int S = 2048, ROWQ = 6144;
    __shared__ __align__(16) bf16 smem[4 * 8192 + 64 * 72];
    bf16* Ps = smem + 32768;

    const int idx = blockIdx.x;
    const int qt = 31 - (idx >> 5);
    const int bh = idx & 31;
    const int b = bh >> 4, h = bh & 15;
    const int tid = threadIdx.x;
    const int lane = tid & 63, wave = tid >> 6;
    const int l15 = lane & 15, quad = lane >> 4;
    const int sw = l15 & 7;
    const int q0 = qt * 64;

    const long qoff = (long)(b * S) * ROWQ + h * 128;
    const long koff = qoff + 2048;
    const long voff = (long)bh * 128 * 2048;

#pragma unroll
    for (int i = 0; i < 4; ++i) {
        int L = i * 256 + tid;
        int row = L >> 4, g = L & 15;
        int gs = g ^ (row & 7);
        __builtin_amdgcn_global_load_lds(
            (GLOBAL_U32)(qkv + qoff + (long)(q0 + row) * ROWQ + gs * 8),
            (LDS_U32)(smem + 16384 + L * 8), 16, 0, 0);
        __builtin_amdgcn_global_load_lds(
            (GLOBAL_U32)(qkv + koff + (long)(row) * ROWQ + gs * 8),
            (LDS_U32)(smem + L * 8), 16, 0, 0);
        int rv = L >> 3, gv = L & 7;
        int gvs = gv ^ (rv & 7);
        __builtin_amdgcn_global_load_lds(
            (GLOBAL_U32)(Vt + voff + (long)rv * 2048 + gvs * 8),
            (LDS_U32)(smem + 8192 + L * 8), 16, 0, 0);
    }
    __syncthreads();

    short8 qf[4];
#pragma unroll
    for (int ks = 0; ks < 4; ++ks)
        qf[ks] = *(const short8*)(smem + 16384 + (wave * 16 + l15) * 128 +
                                  ((ks * 4 + quad) ^ sw) * 8);
    __syncthreads();

    float l_part[4] = {0.f, 0.f, 0.f, 0.f};
    floatx4 o_acc[8] = {};

    const float scale = 0.08838834764831845f;
    const float M0 = 8.0f;

    for (int kt = 0; kt <= qt; ++kt) {
        const int cur = kt & 1;
        bf16* Ks = smem + cur * 16384;
        bf16* Vs = Ks + 8192;

        if (kt < qt) {
            bf16* Kn = smem + (1 - cur) * 16384;
            bf16* Vn = Kn + 8192;
#pragma unroll
            for (int i = 0; i < 4; ++i) {
                int L = i * 256 + tid;
                int row = L >> 4, g = L & 15;
                int gs = g ^ (row & 7);
                __builtin_amdgcn_global_load_lds(
                    (GLOBAL_U32)(qkv + koff + (long)((kt + 1) * 64 + row) * ROWQ + gs * 8),
                    (LDS_U32)(Kn + L * 8), 16, 0, 0);
                int rv = L >> 3, gv = L & 7;
                int gvs = gv ^ (rv & 7);
                __builtin_amdgcn_global_load_lds(
                    (GLOBAL_U32)(Vt + voff + (long)rv * 2048 + (kt + 1) * 64 + gvs * 8),
                    (LDS_U32)(Vn + L * 8), 16, 0, 0);
            }
        }

        floatx4 sacc[4] = {};
#pragma unroll
        for (int ks = 0; ks < 4; ++ks)
#pragma unroll
            for (int t = 0; t < 4; ++t) {
                short8 kf = *(const short8*)(Ks + (t * 16 + l15) * 128 +
                                             ((ks * 4 + quad) ^ sw) * 8);
                sacc[t] = __builtin_amdgcn_mfma_f32_16x16x32_bf16(
                    qf[ks], kf, sacc[t], 0, 0, 0);
            }

        if (kt == qt) {
#pragma unroll
            for (int t = 0; t < 4; ++t)
#pragma unroll
                for (int r = 0; r < 4; ++r)
                    if (t * 16 + l15 > wave * 16 + quad * 4 + r)
                        sacc[t][r] = -INFINITY;
        }
#pragma unroll
        for (int t = 0; t < 4; ++t)
#pragma unroll
            for (int r = 0; r < 4; ++r) {
                float p = __expf(sacc[t][r] * scale - M0);
                sacc[t][r] = p;
                l_part[r] += p;
            }

#pragma unroll
        for (int t = 0; t < 4; ++t)
#pragma unroll
            for (int r = 0; r < 4; ++r) {
                int q = wave * 16 + quad * 4 + r;
                Ps[q * 72 + t * 16 + l15] = __float2bfloat16(sacc[t][r]);
            }

#pragma unroll
        for (int ksj = 0; ksj < 2; ++ksj) {
            short8 pf = *(const short8*)(Ps + (wave * 16 + l15) * 72 + ksj * 32 + quad * 8);
#pragma unroll
            for (int dt = 0; dt < 8; ++dt) {
                short8 vf = *(const short8*)(Vs + (dt * 16 + l15) * 64 +
                                             ((ksj * 4 + quad) ^ sw) * 8);
                o_acc[dt] = __builtin_amdgcn_mfma_f32_16x16x32_bf16(
                    pf, vf, o_acc[dt], 0, 0, 0);
            }
        }

        __syncthreads();
    }

    float invl[4];
#pragma unroll
    for (int r = 0; r < 4; ++r) {
        float rs = l_part[r];
        rs += __shfl_xor(rs, 1);
        rs += __shfl_xor(rs, 2);
        rs += __shfl_xor(rs, 4);
        rs += __shfl_xor(rs, 8);
        invl[r] = 1.f / rs;
    }
#pragma unroll
    for (int dt = 0; dt < 8; ++dt)
#pragma unroll
        for (int r = 0; r < 4; ++r) {
            int q = q0 + wave * 16 + quad * 4 + r;
            int d = dt * 16 + l15;
            O[((long)(b * S + q)) * 2048 + h * 128 + d] =
                __float2bfloat16(o_acc[dt][r] * invl[r]);
        }
}

// ---------------------------------------------------------------------------
extern "C" void kernel_launch(void* const* d_in, const int* in_sizes, int n_in,
                              void* d_out, int out_size, void* d_ws, size_t ws_size,
                              hipStream_t stream) {
    const float* x    = (const float*)d_in[0];   // [4096, 2048] fp32
    const float* Wqkv = (const float*)d_in[1];   // [6144, 2048] fp32
    const float* Wout = (const float*)d_in[2];   // [2048, 2048] fp32
    float* out = (float*)d_out;                  // [4096, 2048] fp32

    bf16* xb     = (bf16*)d_ws;                                // 4096*2048
    bf16* Wqkvb  = xb + (size_t)4096 * 2048;                   // 6144*2048
    bf16* Woutb  = Wqkvb + (size_t)6144 * 2048;                // 2048*2048
    bf16* qkv    = Woutb + (size_t)2048 * 2048;                // 4096*6144
    bf16* Vt     = qkv + (size_t)4096 * 6144;                  // 32*128*2048
    bf16* attn_o = Vt + (size_t)32 * 128 * 2048;               // 4096*2048

    convert_f32_bf16<<<1024, 256, 0, stream>>>(x,    xb,    (long)4096 * 2048);
    convert_f32_bf16<<<1024, 256, 0, stream>>>(Wqkv, Wqkvb, (long)6144 * 2048);
    convert_f32_bf16<<<1024, 256, 0, stream>>>(Wout, Woutb, (long)2048 * 2048);

    // QKV GEMM: 256^2 tile, grid 16x24 = 384 wgs (multiple of 8)
    gemm_bt_256<<<dim3(384), 512, 0, stream>>>(xb, Wqkvb, qkv, 4096, 6144, 2048);

    dim3 g2(2048 / 32, 128 / 32, 32);
    transpose_v<<<g2, 256, 0, stream>>>(qkv, Vt);

    attn_kernel<<<1024, 256, 0, stream>>>(qkv, Vt, attn_o);

    dim3 g4(2048 / 128, 4096 / 128);
    gemm_bt<float><<<g4, 256, 0, stream>>>(attn_o, Woutb, out, 4096, 2048, 2048);
}